// Round 1
// baseline (623.133 us; speedup 1.0000x reference)
//
#include <hip/hip_runtime.h>
#include <hip/hip_bf16.h>
#include <cstdint>
#include <cstddef>

// ---------------------------------------------------------------------------
// SelfAttentionV1: out = softmax((x Wq^T)(x Wk^T)^T / 32) (x Wv^T)
// N=8192, D=1024. All GEMMs via bf16 MFMA 16x16x32, fp32 accumulate.
// Round 0: m97-style 128x128 tile GEMM reused 5x + materialized S in ws.
// ---------------------------------------------------------------------------

typedef __attribute__((ext_vector_type(8))) short short8;     // bf16x8 MFMA frag
typedef __attribute__((ext_vector_type(8))) unsigned short ushort8;
typedef __attribute__((ext_vector_type(4))) float f32x4;

__device__ __forceinline__ unsigned short f2bf(float f) {
  unsigned u = __float_as_uint(f);
  u += 0x7fffu + ((u >> 16) & 1u);      // round-to-nearest-even
  return (unsigned short)(u >> 16);
}
__device__ __forceinline__ float bf2f(unsigned short h) {
  return __uint_as_float(((unsigned)h) << 16);
}

// async global->LDS, 16 bytes per lane (wave-uniform LDS base + lane*16)
__device__ __forceinline__ void glds16(const void* g, void* l) {
  __builtin_amdgcn_global_load_lds((__attribute__((address_space(1))) void*)g,
                                   (__attribute__((address_space(3))) void*)l,
                                   16, 0, 0);
}

// ---- fp32 -> bf16 cast, 8 elems/thread, n8 = n/8 ----
__global__ __launch_bounds__(256) void cast_kernel(const float* __restrict__ in,
                                                   unsigned short* __restrict__ out,
                                                   int n8) {
  int i = blockIdx.x * 256 + threadIdx.x;
  if (i >= n8) return;
  const f32x4* in4 = (const f32x4*)in;
  f32x4 a = in4[2 * i];
  f32x4 b = in4[2 * i + 1];
  ushort8 o;
#pragma unroll
  for (int j = 0; j < 4; ++j) o[j] = f2bf(a[j]);
#pragma unroll
  for (int j = 0; j < 4; ++j) o[4 + j] = f2bf(b[j]);
  ((ushort8*)out)[i] = o;
}

// ---------------------------------------------------------------------------
// C[M,N] = scale * A[M,K] * B[N,K]^T   (A,B bf16 as ushort; C = bf16 or f32)
// 128x128 block, BK=32, 256 threads = 4 waves in 2x2, each wave 64x64 (4x4
// frags of 16x16x32). Staging via global_load_lds dwordx4 (16B/lane).
// M,N multiples of 128; K multiple of 32. No bounds checks.
// ---------------------------------------------------------------------------
#define BM 128
#define BN 128
#define BKK 32

template <typename OutT>
__global__ __launch_bounds__(256, 2) void gemm_bt(
    const unsigned short* __restrict__ A, const unsigned short* __restrict__ B,
    OutT* __restrict__ C, int M, int N, int K, float scale) {
  __shared__ unsigned short As[BM * BKK];  // 8 KB, rows of 64 B
  __shared__ unsigned short Bs[BN * BKK];  // 8 KB

  const int t = threadIdx.x;
  const int lane = t & 63, w = t >> 6;
  const int wr = w >> 1, wc = w & 1;           // wave 2x2
  const int lrow = lane & 15, kgrp = lane >> 4; // frag row / k-group
  const int bm = blockIdx.y, bn = blockIdx.x;

  f32x4 acc[4][4];
#pragma unroll
  for (int m = 0; m < 4; ++m)
#pragma unroll
    for (int n = 0; n < 4; ++n) acc[m][n] = (f32x4)(0.0f);

  // staging: 8KB tile = 2 insts x 4 waves x 64 lanes x 16B
  const int o0 = w * 1024 + lane * 16;  // byte offset in tile, inst 0
  const int o1 = o0 + 4096;             // inst 1
  const int r0 = o0 >> 6, c0 = o0 & 63; // tile row (64B rows), byte-in-row
  const int r1 = o1 >> 6, c1 = o1 & 63;

  const size_t ldab = (size_t)K * 2;  // row bytes
  const char* Abase = (const char*)A + (size_t)bm * BM * ldab;
  const char* Bbase = (const char*)B + (size_t)bn * BN * ldab;
  char* AsB = (char*)As;
  char* BsB = (char*)Bs;

  for (int kt = 0; kt < K; kt += BKK) {
    __syncthreads();  // previous iter's LDS reads done
    glds16(Abase + (size_t)r0 * ldab + (size_t)kt * 2 + c0, AsB + w * 1024);
    glds16(Abase + (size_t)r1 * ldab + (size_t)kt * 2 + c1, AsB + 4096 + w * 1024);
    glds16(Bbase + (size_t)r0 * ldab + (size_t)kt * 2 + c0, BsB + w * 1024);
    glds16(Bbase + (size_t)r1 * ldab + (size_t)kt * 2 + c1, BsB + 4096 + w * 1024);
    __syncthreads();  // vmcnt(0) drain + barrier

    short8 aF[4], bF[4];
#pragma unroll
    for (int m = 0; m < 4; ++m)
      aF[m] = *(const short8*)&As[(wr * 64 + m * 16 + lrow) * BKK + kgrp * 8];
#pragma unroll
    for (int n = 0; n < 4; ++n)
      bF[n] = *(const short8*)&Bs[(wc * 64 + n * 16 + lrow) * BKK + kgrp * 8];
#pragma unroll
    for (int m = 0; m < 4; ++m)
#pragma unroll
      for (int n = 0; n < 4; ++n)
        acc[m][n] = __builtin_amdgcn_mfma_f32_16x16x32_bf16(aF[m], bF[n],
                                                            acc[m][n], 0, 0, 0);
  }

  // epilogue: D row=(lane>>4)*4+r, col=lane&15 (m89-verified layout)
  const int crow = bm * BM + wr * 64;
  const int ccol = bn * BN + wc * 64;
#pragma unroll
  for (int m = 0; m < 4; ++m) {
#pragma unroll
    for (int n = 0; n < 4; ++n) {
      int r = crow + m * 16 + kgrp * 4;
      int c = ccol + n * 16 + lrow;
      f32x4 v = acc[m][n];
#pragma unroll
      for (int j = 0; j < 4; ++j) {
        float val = v[j] * scale;
        if (sizeof(OutT) == 2) {
          ((unsigned short*)C)[(size_t)(r + j) * N + c] = f2bf(val);
        } else {
          ((float*)C)[(size_t)(r + j) * N + c] = val;
        }
      }
    }
  }
}

// ---- row softmax in place over bf16 S, ncol = 8192 (256 thr x 32 elems) ----
__global__ __launch_bounds__(256) void softmax_kernel(unsigned short* __restrict__ S,
                                                      int ncol) {
  const int t = threadIdx.x;
  unsigned short* rp = S + (size_t)blockIdx.x * ncol;
  ushort8* rv = (ushort8*)rp;
  const int nch = ncol >> 11;  // chunks of 2048 elems (256 thr * 8)
  float f[32];
#pragma unroll
  for (int c = 0; c < 4; ++c) {
    if (c < nch) {
      ushort8 v = rv[c * 256 + t];
#pragma unroll
      for (int j = 0; j < 8; ++j) f[c * 8 + j] = bf2f(v[j]);
    }
  }
  float m = -1e30f;
#pragma unroll
  for (int i = 0; i < 32; ++i) m = fmaxf(m, f[i]);
#pragma unroll
  for (int o = 32; o; o >>= 1) m = fmaxf(m, __shfl_xor(m, o));
  __shared__ float red[8];
  if ((t & 63) == 0) red[t >> 6] = m;
  __syncthreads();
  m = fmaxf(fmaxf(red[0], red[1]), fmaxf(red[2], red[3]));

  float s = 0.0f;
#pragma unroll
  for (int i = 0; i < 32; ++i) {
    f[i] = __expf(f[i] - m);
    s += f[i];
  }
#pragma unroll
  for (int o = 32; o; o >>= 1) s += __shfl_xor(s, o);
  if ((t & 63) == 0) red[4 + (t >> 6)] = s;
  __syncthreads();
  s = red[4] + red[5] + red[6] + red[7];
  float inv = 1.0f / s;
#pragma unroll
  for (int c = 0; c < 4; ++c) {
    if (c < nch) {
      ushort8 v;
#pragma unroll
      for (int j = 0; j < 8; ++j) v[j] = f2bf(f[c * 8 + j] * inv);
      rv[c * 256 + t] = v;
    }
  }
}

// ---- 64x64 tiled transpose: out[C][R] = in[R][C] (bf16) ----
__global__ __launch_bounds__(256) void transpose_kernel(
    const unsigned short* __restrict__ in, unsigned short* __restrict__ out,
    int R, int Ccols) {
  __shared__ unsigned short tile[64][65];
  const int tx = threadIdx.x & 63, ty = threadIdx.x >> 6;
  const int r0 = blockIdx.y * 64, c0 = blockIdx.x * 64;
#pragma unroll
  for (int i = 0; i < 16; ++i) {
    int r = ty * 16 + i;
    tile[r][tx] = in[(size_t)(r0 + r) * Ccols + c0 + tx];
  }
  __syncthreads();
#pragma unroll
  for (int i = 0; i < 16; ++i) {
    int r = ty * 16 + i;
    out[(size_t)(c0 + r) * R + r0 + tx] = tile[tx][r];
  }
}

extern "C" void kernel_launch(void* const* d_in, const int* in_sizes, int n_in,
                              void* d_out, int out_size, void* d_ws, size_t ws_size,
                              hipStream_t stream) {
  (void)in_sizes; (void)n_in; (void)out_size; (void)ws_size;
  const int N = 8192, D = 1024;
  const float* x  = (const float*)d_in[0];
  const float* Wq = (const float*)d_in[1];
  const float* Wk = (const float*)d_in[2];
  const float* Wv = (const float*)d_in[3];
  float* out = (float*)d_out;

  char* ws = (char*)d_ws;
  size_t off = 0;
  auto alloc = [&](size_t bytes) { char* p = ws + off; off += bytes; return p; };
  unsigned short* xh  = (unsigned short*)alloc((size_t)N * D * 2);  // 16.8 MB
  unsigned short* Wqh = (unsigned short*)alloc((size_t)D * D * 2);  // 2 MB
  unsigned short* Wkh = (unsigned short*)alloc((size_t)D * D * 2);
  unsigned short* Wvh = (unsigned short*)alloc((size_t)D * D * 2);
  unsigned short* Qh  = (unsigned short*)alloc((size_t)N * D * 2);  // 16.8 MB
  unsigned short* Kh  = (unsigned short*)alloc((size_t)N * D * 2);
  unsigned short* Vh  = (unsigned short*)alloc((size_t)N * D * 2);
  unsigned short* S   = (unsigned short*)alloc((size_t)N * N * 2);  // 134.2 MB
  unsigned short* Vth = xh;  // reuse: xh dead after the V GEMM
  // total ws: ~207.6 MB

  // casts
  cast_kernel<<<(N * D / 8) / 256, 256, 0, stream>>>(x, xh, N * D / 8);
  cast_kernel<<<(D * D / 8) / 256, 256, 0, stream>>>(Wq, Wqh, D * D / 8);
  cast_kernel<<<(D * D / 8) / 256, 256, 0, stream>>>(Wk, Wkh, D * D / 8);
  cast_kernel<<<(D * D / 8) / 256, 256, 0, stream>>>(Wv, Wvh, D * D / 8);

  // Q,K,V = x @ W^T   [8192,1024]
  dim3 gqkv(D / BN, N / BM);
  gemm_bt<unsigned short><<<gqkv, 256, 0, stream>>>(xh, Wqh, Qh, N, D, D, 1.0f);
  gemm_bt<unsigned short><<<gqkv, 256, 0, stream>>>(xh, Wkh, Kh, N, D, D, 1.0f);
  gemm_bt<unsigned short><<<gqkv, 256, 0, stream>>>(xh, Wvh, Vh, N, D, D, 1.0f);

  // S = Q @ K^T * (1/32)   [8192,8192]
  dim3 gs(N / BN, N / BM);
  gemm_bt<unsigned short><<<gs, 256, 0, stream>>>(Qh, Kh, S, N, N, D, 0.03125f);

  // softmax rows (in place)
  softmax_kernel<<<N, 256, 0, stream>>>(S, N);

  // Vt = V^T  [1024,8192]
  transpose_kernel<<<dim3(D / 64, N / 64), 256, 0, stream>>>(Vh, Vth, N, D);

  // out = P @ Vt^T  [8192,1024]  (fp32 out)
  dim3 go(D / BN, N / BM);
  gemm_bt<float><<<go, 256, 0, stream>>>(S, Vth, out, N, D, N, 1.0f);
}

// Round 2
// 608.851 us; speedup vs baseline: 1.0235x; 1.0235x over previous
//
#include <hip/hip_runtime.h>
#include <hip/hip_bf16.h>
#include <cstdint>
#include <cstddef>

// ---------------------------------------------------------------------------
// SelfAttentionV1: out = softmax((x Wq^T)(x Wk^T)^T / 32) (x Wv^T)
// N=8192, D=1024. Round 2: 256x256/BK=32 ring-4 counted-vmcnt MFMA GEMM
// (T2 swizzle + T3/T4 pipeline + T5 setprio + T1 XCD chunking), QKV fused,
// PV split-K x2 for full-chip occupancy.
// ---------------------------------------------------------------------------

typedef __attribute__((ext_vector_type(8))) short short8;     // bf16x8 MFMA frag
typedef __attribute__((ext_vector_type(8))) unsigned short ushort8;
typedef __attribute__((ext_vector_type(4))) float f32x4;

#define FENCE asm volatile("" ::: "memory")

__device__ __forceinline__ unsigned short f2bf(float f) {
  unsigned u = __float_as_uint(f);
  u += 0x7fffu + ((u >> 16) & 1u);      // round-to-nearest-even
  return (unsigned short)(u >> 16);
}
__device__ __forceinline__ float bf2f(unsigned short h) {
  return __uint_as_float(((unsigned)h) << 16);
}

// async global->LDS, 16 bytes per lane (wave-uniform LDS base + lane*16)
__device__ __forceinline__ void glds16(const void* g, void* l) {
  __builtin_amdgcn_global_load_lds((__attribute__((address_space(1))) void*)g,
                                   (__attribute__((address_space(3))) void*)l,
                                   16, 0, 0);
}

// ---- fp32 -> bf16 cast, 8 elems/thread ----
__global__ __launch_bounds__(256) void cast_kernel(const float* __restrict__ in,
                                                   unsigned short* __restrict__ out,
                                                   int n8) {
  int i = blockIdx.x * 256 + threadIdx.x;
  if (i >= n8) return;
  const f32x4* in4 = (const f32x4*)in;
  f32x4 a = in4[2 * i];
  f32x4 b = in4[2 * i + 1];
  ushort8 o;
#pragma unroll
  for (int j = 0; j < 4; ++j) o[j] = f2bf(a[j]);
#pragma unroll
  for (int j = 0; j < 4; ++j) o[4 + j] = f2bf(b[j]);
  ((ushort8*)out)[i] = o;
}

// ---------------------------------------------------------------------------
// GEMM core: C[gm0..+256, gn0..+256] = scale * A * B^T  (A,B bf16 [*, K] rows)
// 512 thr = 8 waves (2M x 4N), wave-out 128x64 (8x4 frags of 16x16x32).
// BK=32, RING=4 LDS slots (128 KiB), prefetch distance 2, vmcnt(4) boundary.
// LDS plane [256 rows][32 cols] bf16 (64B rows), swizzle: colbyte ^=
// ((row>>1)&3)<<4  -> each 16-lane ds_read_b128 beat covers all 8 bank-quads.
// Staging pre-swizzles the GLOBAL source (LDS dest stays linear, rule #21).
// ---------------------------------------------------------------------------
#define MFMA_OP(mi, ni, av, bv) \
  acc[mi][ni] = __builtin_amdgcn_mfma_f32_16x16x32_bf16(av, bv, acc[mi][ni], 0, 0, 0)

template <typename OutT>
__device__ __forceinline__ void gemm_core(
    const unsigned short* __restrict__ A, const unsigned short* __restrict__ B,
    OutT* __restrict__ C, int ldc, size_t ldab /*row bytes*/, int NT,
    int gm0, int gn0, float scale, char* lA, char* lB) {
  const int tid = threadIdx.x;
  const int lane = tid & 63, w = tid >> 6;
  const int wm = w >> 2, wn = w & 3;            // 2M x 4N wave grid

  // ---- staging (writer) per-lane constants ----
  // call c covers plane rows [w*32+c*16, +16); lane -> row rc + (lane>>2),
  // 16B slot (lane&3); source column pre-swizzled by ((row>>1)&3)<<4 which
  // reduces to ((lane>>3)&3)<<4 (lane-constant).
  const int rc0 = w * 32 + (lane >> 2);
  const int rc1 = rc0 + 16;
  const int scol = ((lane & 3) << 4) ^ (((lane >> 3) & 3) << 4);
  const char* pA0 = (const char*)A + (size_t)(gm0 + rc0) * ldab + scol;
  const char* pA1 = (const char*)A + (size_t)(gm0 + rc1) * ldab + scol;
  const char* pB0 = (const char*)B + (size_t)(gn0 + rc0) * ldab + scol;
  const char* pB1 = (const char*)B + (size_t)(gn0 + rc1) * ldab + scol;
  char* dA = lA + w * 2048;   // + slot*16384 (+1024 for c=1)
  char* dB = lB + w * 2048;

  // ---- reader per-lane constants ----
  // frag: row = base + mi*16 + (lane&15), col elems (lane>>4)*8; swizzle term
  // ((row>>1)&3)<<4 reduces to ((lane>>1)&3)<<4 (bases are multiples of 16).
  const int colb = ((lane >> 4) << 4) ^ (((lane >> 1) & 3) << 4);
  const int aoff = (wm * 128 + (lane & 15)) * 64 + colb;
  const int boff = (wn * 64 + (lane & 15)) * 64 + colb;

  f32x4 acc[8][4];
#pragma unroll
  for (int m = 0; m < 8; ++m)
#pragma unroll
    for (int n = 0; n < 4; ++n) acc[m][n] = (f32x4)(0.0f);

  // ---- prologue: stage tiles 0,1; wait tile 0 (vmcnt(4) leaves t1 in flight)
  for (int t = 0; t < 2; ++t) {
    glds16(pA0 + (size_t)t * 64, dA + t * 16384);
    glds16(pA1 + (size_t)t * 64, dA + t * 16384 + 1024);
    glds16(pB0 + (size_t)t * 64, dB + t * 16384);
    glds16(pB1 + (size_t)t * 64, dB + t * 16384 + 1024);
  }
  asm volatile("s_waitcnt vmcnt(4)" ::: "memory");
  __builtin_amdgcn_s_barrier();
  FENCE;

  for (int t = 0; t < NT; ++t) {
    const int slot = t & 3;
    const char* As = lA + slot * 16384;
    const char* Bs = lB + slot * 16384;
    const bool stg = (t + 2 < NT);
    const int s2 = (t + 2) & 3;
    const size_t go = (size_t)(t + 2) * 64;
    short8 a0, a1, a2, a3, b0, b1, b2, b3;

    // ---- phase 0: stage A.c0(t+2) | read A[mi0-3], B[ni0-1] | 8 MFMA
    if (stg) glds16(pA0 + go, dA + s2 * 16384);
    a0 = *(const short8*)(As + aoff);
    a1 = *(const short8*)(As + aoff + 1024);
    a2 = *(const short8*)(As + aoff + 2048);
    a3 = *(const short8*)(As + aoff + 3072);
    b0 = *(const short8*)(Bs + boff);
    b1 = *(const short8*)(Bs + boff + 1024);
    __builtin_amdgcn_s_setprio(1);
    MFMA_OP(0, 0, a0, b0); MFMA_OP(0, 1, a0, b1);
    MFMA_OP(1, 0, a1, b0); MFMA_OP(1, 1, a1, b1);
    MFMA_OP(2, 0, a2, b0); MFMA_OP(2, 1, a2, b1);
    MFMA_OP(3, 0, a3, b0); MFMA_OP(3, 1, a3, b1);
    __builtin_amdgcn_s_setprio(0);
    FENCE; __builtin_amdgcn_s_barrier(); FENCE;

    // ---- phase 1: stage A.c1 | read B[ni2-3] | 8 MFMA
    if (stg) glds16(pA1 + go, dA + s2 * 16384 + 1024);
    b2 = *(const short8*)(Bs + boff + 2048);
    b3 = *(const short8*)(Bs + boff + 3072);
    __builtin_amdgcn_s_setprio(1);
    MFMA_OP(0, 2, a0, b2); MFMA_OP(0, 3, a0, b3);
    MFMA_OP(1, 2, a1, b2); MFMA_OP(1, 3, a1, b3);
    MFMA_OP(2, 2, a2, b2); MFMA_OP(2, 3, a2, b3);
    MFMA_OP(3, 2, a3, b2); MFMA_OP(3, 3, a3, b3);
    __builtin_amdgcn_s_setprio(0);
    FENCE; __builtin_amdgcn_s_barrier(); FENCE;

    // ---- phase 2: stage B.c0 | read A[mi4-7] | 8 MFMA
    if (stg) glds16(pB0 + go, dB + s2 * 16384);
    a0 = *(const short8*)(As + aoff + 4096);
    a1 = *(const short8*)(As + aoff + 5120);
    a2 = *(const short8*)(As + aoff + 6144);
    a3 = *(const short8*)(As + aoff + 7168);
    __builtin_amdgcn_s_setprio(1);
    MFMA_OP(4, 0, a0, b0); MFMA_OP(4, 1, a0, b1);
    MFMA_OP(5, 0, a1, b0); MFMA_OP(5, 1, a1, b1);
    MFMA_OP(6, 0, a2, b0); MFMA_OP(6, 1, a2, b1);
    MFMA_OP(7, 0, a3, b0); MFMA_OP(7, 1, a3, b1);
    __builtin_amdgcn_s_setprio(0);
    FENCE; __builtin_amdgcn_s_barrier(); FENCE;

    // ---- phase 3: stage B.c1 | 8 MFMA | counted wait | barrier
    if (stg) glds16(pB1 + go, dB + s2 * 16384 + 1024);
    __builtin_amdgcn_s_setprio(1);
    MFMA_OP(4, 2, a0, b2); MFMA_OP(4, 3, a0, b3);
    MFMA_OP(5, 2, a1, b2); MFMA_OP(5, 3, a1, b3);
    MFMA_OP(6, 2, a2, b2); MFMA_OP(6, 3, a2, b3);
    MFMA_OP(7, 2, a3, b2); MFMA_OP(7, 3, a3, b3);
    __builtin_amdgcn_s_setprio(0);
    if (stg) asm volatile("s_waitcnt vmcnt(4)" ::: "memory");  // t+1 complete
    else     asm volatile("s_waitcnt vmcnt(0)" ::: "memory");  // drain tail
    __builtin_amdgcn_s_barrier();
    FENCE;
  }

  // ---- epilogue: C row=(lane>>4)*4+j, col=lane&15 (m89-verified layout)
  const int r0 = gm0 + wm * 128 + ((lane >> 4) << 2);
  const int c0 = gn0 + wn * 64 + (lane & 15);
#pragma unroll
  for (int mi = 0; mi < 8; ++mi) {
#pragma unroll
    for (int ni = 0; ni < 4; ++ni) {
      f32x4 v = acc[mi][ni];
#pragma unroll
      for (int j = 0; j < 4; ++j) {
        float val = v[j] * scale;
        size_t idx = (size_t)(r0 + mi * 16 + j) * ldc + (c0 + ni * 16);
        if (sizeof(OutT) == 2) ((unsigned short*)C)[idx] = f2bf(val);
        else                   ((float*)C)[idx] = val;
      }
    }
  }
}

// bijective XCD chunking: consecutive logical blocks land on the same XCD
__device__ __forceinline__ void swz_block(int& bx, int& by, int& bz) {
  const int gx = gridDim.x, gy = gridDim.y;
  const int f = (blockIdx.z * gy + blockIdx.y) * gx + blockIdx.x;
  const int nwg = gx * gy * gridDim.z;      // all grids are multiples of 8
  const int q = nwg >> 3;
  const int l = (f & 7) * q + (f >> 3);
  bx = l % gx;
  const int r = l / gx;
  by = r % gy;
  bz = r / gy;
}

__global__ __launch_bounds__(512, 2) void gemm_s_kernel(
    const unsigned short* __restrict__ Q, const unsigned short* __restrict__ Kh,
    unsigned short* __restrict__ S) {
  __shared__ char lA[4 * 16384];
  __shared__ char lB[4 * 16384];
  int bx, by, bz; swz_block(bx, by, bz);
  gemm_core<unsigned short>(Q, Kh, S, 8192, 2048, 32, by * 256, bx * 256,
                            0.03125f, lA, lB);
}

__global__ __launch_bounds__(512, 2) void gemm_qkv_kernel(
    const unsigned short* __restrict__ X,
    const unsigned short* __restrict__ Wq, const unsigned short* __restrict__ Wk,
    const unsigned short* __restrict__ Wv,
    unsigned short* __restrict__ Qo, unsigned short* __restrict__ Ko,
    unsigned short* __restrict__ Vo) {
  __shared__ char lA[4 * 16384];
  __shared__ char lB[4 * 16384];
  int bx, by, bz; swz_block(bx, by, bz);
  const unsigned short* B = (bz == 0) ? Wq : (bz == 1) ? Wk : Wv;
  unsigned short* C = (bz == 0) ? Qo : (bz == 1) ? Ko : Vo;
  gemm_core<unsigned short>(X, B, C, 1024, 2048, 32, by * 256, bx * 256,
                            1.0f, lA, lB);
}

// PV with split-K x2: z=0 writes d_out, z=1 writes partial buffer
__global__ __launch_bounds__(512, 2) void gemm_pv_kernel(
    const unsigned short* __restrict__ S, const unsigned short* __restrict__ Vt,
    float* __restrict__ O, float* __restrict__ P1) {
  __shared__ char lA[4 * 16384];
  __shared__ char lB[4 * 16384];
  int bx, by, bz; swz_block(bx, by, bz);
  const unsigned short* A = S + (size_t)bz * 4096;   // k-offset 4096 elems
  const unsigned short* B = Vt + (size_t)bz * 4096;
  float* C = bz ? P1 : O;
  gemm_core<float>(A, B, C, 1024, 16384, 128, by * 256, bx * 256, 1.0f, lA, lB);
}

__global__ __launch_bounds__(256) void add_kernel(float* __restrict__ out,
                                                  const float* __restrict__ p,
                                                  int n4) {
  int i = blockIdx.x * 256 + threadIdx.x;
  if (i < n4) {
    f32x4 a = ((const f32x4*)out)[i];
    f32x4 b = ((const f32x4*)p)[i];
    ((f32x4*)out)[i] = a + b;
  }
}

// ---- row softmax in place over bf16 S, ncol = 8192 (256 thr x 32 elems) ----
__global__ __launch_bounds__(256) void softmax_kernel(unsigned short* __restrict__ S,
                                                      int ncol) {
  const int t = threadIdx.x;
  unsigned short* rp = S + (size_t)blockIdx.x * ncol;
  ushort8* rv = (ushort8*)rp;
  float f[32];
#pragma unroll
  for (int c = 0; c < 4; ++c) {
    ushort8 v = rv[c * 256 + t];
#pragma unroll
    for (int j = 0; j < 8; ++j) f[c * 8 + j] = bf2f(v[j]);
  }
  float m = -1e30f;
#pragma unroll
  for (int i = 0; i < 32; ++i) m = fmaxf(m, f[i]);
#pragma unroll
  for (int o = 32; o; o >>= 1) m = fmaxf(m, __shfl_xor(m, o));
  __shared__ float red[8];
  if ((t & 63) == 0) red[t >> 6] = m;
  __syncthreads();
  m = fmaxf(fmaxf(red[0], red[1]), fmaxf(red[2], red[3]));

  float s = 0.0f;
#pragma unroll
  for (int i = 0; i < 32; ++i) {
    f[i] = __expf(f[i] - m);
    s += f[i];
  }
#pragma unroll
  for (int o = 32; o; o >>= 1) s += __shfl_xor(s, o);
  if ((t & 63) == 0) red[4 + (t >> 6)] = s;
  __syncthreads();
  s = red[4] + red[5] + red[6] + red[7];
  float inv = 1.0f / s;
#pragma unroll
  for (int c = 0; c < 4; ++c) {
    ushort8 v;
#pragma unroll
    for (int j = 0; j < 8; ++j) v[j] = f2bf(f[c * 8 + j] * inv);
    rv[c * 256 + t] = v;
  }
}

// ---- 64x64 tiled transpose: out[C][R] = in[R][C] (bf16) ----
__global__ __launch_bounds__(256) void transpose_kernel(
    const unsigned short* __restrict__ in, unsigned short* __restrict__ out,
    int R, int Ccols) {
  __shared__ unsigned short tile[64][65];
  const int tx = threadIdx.x & 63, ty = threadIdx.x >> 6;
  const int r0 = blockIdx.y * 64, c0 = blockIdx.x * 64;
#pragma unroll
  for (int i = 0; i < 16; ++i) {
    int r = ty * 16 + i;
    tile[r][tx] = in[(size_t)(r0 + r) * Ccols + c0 + tx];
  }
  __syncthreads();
#pragma unroll
  for (int i = 0; i < 16; ++i) {
    int r = ty * 16 + i;
    out[(size_t)(c0 + r) * R + r0 + tx] = tile[tx][r];
  }
}

extern "C" void kernel_launch(void* const* d_in, const int* in_sizes, int n_in,
                              void* d_out, int out_size, void* d_ws, size_t ws_size,
                              hipStream_t stream) {
  (void)in_sizes; (void)n_in; (void)out_size; (void)ws_size;
  const int N = 8192, D = 1024;
  const float* x  = (const float*)d_in[0];
  const float* Wq = (const float*)d_in[1];
  const float* Wk = (const float*)d_in[2];
  const float* Wv = (const float*)d_in[3];
  float* out = (float*)d_out;

  char* ws = (char*)d_ws;
  size_t off = 0;
  auto alloc = [&](size_t bytes) { char* p = ws + off; off += bytes; return p; };
  unsigned short* xh  = (unsigned short*)alloc((size_t)N * D * 2);  // 16.8 MB
  unsigned short* Wqh = (unsigned short*)alloc((size_t)D * D * 2);  // 2 MB
  unsigned short* Wkh = (unsigned short*)alloc((size_t)D * D * 2);
  unsigned short* Wvh = (unsigned short*)alloc((size_t)D * D * 2);
  unsigned short* Qh  = (unsigned short*)alloc((size_t)N * D * 2);  // 16.8 MB
  unsigned short* Kh  = (unsigned short*)alloc((size_t)N * D * 2);
  unsigned short* Vh  = (unsigned short*)alloc((size_t)N * D * 2);
  unsigned short* S   = (unsigned short*)alloc((size_t)N * N * 2);  // 134.2 MB
  unsigned short* Vth = xh;            // xh dead after QKV
  float* Pbuf = (float*)Qh;            // Qh+Kh (33.6 MB) dead after S-GEMM

  // casts
  cast_kernel<<<(N * D / 8) / 256, 256, 0, stream>>>(x, xh, N * D / 8);
  cast_kernel<<<(D * D / 8) / 256, 256, 0, stream>>>(Wq, Wqh, D * D / 8);
  cast_kernel<<<(D * D / 8) / 256, 256, 0, stream>>>(Wk, Wkh, D * D / 8);
  cast_kernel<<<(D * D / 8) / 256, 256, 0, stream>>>(Wv, Wvh, D * D / 8);

  // Q,K,V = x @ W^T  (fused over z)
  gemm_qkv_kernel<<<dim3(4, 32, 3), 512, 0, stream>>>(xh, Wqh, Wkh, Wvh,
                                                      Qh, Kh, Vh);

  // S = Q @ K^T * (1/32)
  gemm_s_kernel<<<dim3(32, 32), 512, 0, stream>>>(Qh, Kh, S);

  // softmax rows (in place)
  softmax_kernel<<<N, 256, 0, stream>>>(S, N);

  // Vt = V^T  [1024,8192]
  transpose_kernel<<<dim3(D / 64, N / 64), 256, 0, stream>>>(Vh, Vth, N, D);

  // out = P @ Vt^T  (split-K x2, full-chip grid)
  gemm_pv_kernel<<<dim3(4, 32, 2), 512, 0, stream>>>(S, Vth, out, Pbuf);

  // out += partial
  add_kernel<<<(N * D / 4) / 256, 256, 0, stream>>>(out, Pbuf, N * D / 4);
}